// Round 6
// baseline (4649.206 us; speedup 1.0000x reference)
//
#include <hip/hip_runtime.h>
#include <hip/hip_bf16.h>
#include <hip/hip_fp16.h>

// ---------------------------------------------------------------------------
// MGAN forward. fp16 MFMA; block-local LSTM scan (NO cross-block sync).
//   B=256 S=128 A=8 L=32 D=H=300 NC=3 VOCAB=32000
// MFMA 16x16x32_f16 fragment scheme (validated rounds 2-3):
//   A-frag: lane holds A[m = l&15][k = (l>>4)*8 + j]
//   B-frag (B^T [n][k]): lane holds B[n = l&15][k = (l>>4)*8 + j]
//   D:      lane,reg r -> D[m = (l>>4)*4 + r][n = l&15]
// P PADDED: pitch 2432 = [dir 2][gate 4][304], K padded 300->320.
// Scan: grid (16 bgroups, 2 dirs); each block owns ALL j for 16 batches and
// loops all T steps internally. h in LDS Ah[16][328] (pad->conflict-free);
// Whh streamed from L2; gates stay in the MFMA owner lanes' registers
// (wave w owns jj-tiles {5w+i}, all 4 gates per tile -> all 4 gate preacts
// for a (b,jj) cell land in one lane); c-state in registers.
// ---------------------------------------------------------------------------

#define NB   256
#define NS   128
#define NA   8
#define NL   32
#define ND   300
#define NH   300
#define NPAD  2432      // 2*4*304
#define PPITCH 2432
#define KP    320
#define TOK_CTX 32768
#define TOK_ALL 34816

typedef _Float16 half8 __attribute__((ext_vector_type(8)));
typedef float    f32x4 __attribute__((ext_vector_type(4)));

// ---------------- K0: sequence lengths ----------------
__global__ void k_lengths(const int* __restrict__ text, const int* __restrict__ aspect,
                          const int* __restrict__ left, int* __restrict__ lens) {
  int b = threadIdx.x;
  if (b >= NB) return;
  int ll = 0; for (int i = 0; i < NL; i++) ll += (left[b*NL + i] != 0);
  int cl = 0; for (int i = 0; i < NS; i++) cl += (text[b*NS + i] != 0);
  int al = 0; for (int i = 0; i < NA; i++) al += (aspect[b*NA + i] != 0);
  lens[b] = ll; lens[NB + b] = cl; lens[2*NB + b] = al;
}

// ---------------- converters ----------------
__global__ void k_cvt_emb(const float* __restrict__ emb, _Float16* __restrict__ emb16) {
  const long N = (long)32000 * KP;
  for (long i = (long)blockIdx.x*blockDim.x + threadIdx.x; i < N; i += (long)gridDim.x*blockDim.x) {
    long v = i / KP; int k = (int)(i - v*KP);
    emb16[i] = (k < ND) ? (_Float16)emb[v*ND + k] : (_Float16)0.f;
  }
}

// y==0: Wih16, y==1: Whh16, y==2: bias_sum  (layout [d][g][304][320], zero pad)
__global__ void k_cvt_w(const float* __restrict__ Wih_f, const float* __restrict__ Wih_b,
                        const float* __restrict__ Whh_f, const float* __restrict__ Whh_b,
                        const float* __restrict__ bih_f, const float* __restrict__ bhh_f,
                        const float* __restrict__ bih_b, const float* __restrict__ bhh_b,
                        _Float16* __restrict__ Wih16, _Float16* __restrict__ Whh16,
                        float* __restrict__ bias_sum) {
  int y = blockIdx.y;
  if (y < 2) {
    const long N = (long)NPAD * KP;
    const float* sf = y ? Whh_f : Wih_f;
    const float* sb = y ? Whh_b : Wih_b;
    _Float16* dst = y ? Whh16 : Wih16;
    for (long i = (long)blockIdx.x*blockDim.x + threadIdx.x; i < N; i += (long)gridDim.x*blockDim.x) {
      long row = i / KP; int k = (int)(i - row*KP);
      int d = (int)(row / 1216); int rem = (int)(row - (long)d*1216);
      int g = rem / 304; int jj = rem - g*304;
      float v = 0.f;
      if (jj < NH && k < NH) {
        const float* src = d ? sb : sf;
        v = src[(long)(g*NH + jj)*NH + k];
      }
      dst[i] = (_Float16)v;
    }
  } else {
    for (int i = blockIdx.x*blockDim.x + threadIdx.x; i < NPAD; i += gridDim.x*blockDim.x) {
      int d = i / 1216; int rem = i - d*1216;
      int g = rem / 304; int jj = rem - g*304;
      float v = 0.f;
      if (jj < NH) {
        v = d ? (bih_b[g*NH + jj] + bhh_b[g*NH + jj]) : (bih_f[g*NH + jj] + bhh_f[g*NH + jj]);
      }
      bias_sum[i] = v;
    }
  }
}

// ---------------- K1: input projection GEMM via MFMA, LDS-coalesced epilogue ----
__global__ __launch_bounds__(256) void k_inproj(
    const _Float16* __restrict__ emb16, const int* __restrict__ text, const int* __restrict__ aspect,
    const _Float16* __restrict__ Wih16, const float* __restrict__ bias_sum,
    _Float16* __restrict__ P)
{
  const int l = threadIdx.x & 63, w = threadIdx.x >> 6;
  const int m0 = blockIdx.x * 128, n0 = blockIdx.y * 128;
  const int lrow = l & 15, lk = (l >> 4) * 8;
  __shared__ __align__(16) _Float16 Cs[128*136];

  const _Float16* ap[2];
  #pragma unroll
  for (int q = 0; q < 2; q++) {
    int r = m0 + (2*w + q)*16 + lrow;
    int tok = (r < TOK_CTX) ? text[r] : aspect[r - TOK_CTX];
    ap[q] = emb16 + (long)tok*KP + lk;
  }
  const _Float16* bp[8];
  #pragma unroll
  for (int nt = 0; nt < 8; nt++)
    bp[nt] = Wih16 + (long)(n0 + nt*16 + lrow)*KP + lk;

  f32x4 acc[2][8];
  #pragma unroll
  for (int q = 0; q < 2; q++)
    #pragma unroll
    for (int nt = 0; nt < 8; nt++) acc[q][nt] = (f32x4){0.f,0.f,0.f,0.f};

  #pragma unroll
  for (int k0 = 0; k0 < 10; k0++) {
    half8 a0 = *(const half8*)(ap[0] + k0*32);
    half8 a1 = *(const half8*)(ap[1] + k0*32);
    #pragma unroll
    for (int nt = 0; nt < 8; nt++) {
      half8 bb = *(const half8*)(bp[nt] + k0*32);
      acc[0][nt] = __builtin_amdgcn_mfma_f32_16x16x32_f16(a0, bb, acc[0][nt], 0, 0, 0);
      acc[1][nt] = __builtin_amdgcn_mfma_f32_16x16x32_f16(a1, bb, acc[1][nt], 0, 0, 0);
    }
  }

  #pragma unroll
  for (int nt = 0; nt < 8; nt++) {
    float bias = bias_sum[n0 + nt*16 + lrow];
    #pragma unroll
    for (int q = 0; q < 2; q++) {
      int lr = (2*w + q)*16 + (l>>4)*4;
      #pragma unroll
      for (int r = 0; r < 4; r++)
        Cs[(lr + r)*136 + nt*16 + lrow] = (_Float16)(acc[q][nt][r] + bias);
    }
  }
  __syncthreads();
  const int row = threadIdx.x >> 1, ch = (threadIdx.x & 1)*64;
  long gbase = (long)(m0 + row)*PPITCH + n0 + ch;
  #pragma unroll
  for (int i = 0; i < 8; i++) {
    half8 v = *(const half8*)&Cs[row*136 + ch + i*8];
    *(half8*)&P[gbase + i*8] = v;
  }
}

// ---------------- K2: block-local LSTM scan ----------------
// grid (16 bg, 2 d), 256 thr = 4 waves. Each block: 16 batches, all j, T steps.
__global__ __launch_bounds__(256, 1) void k_lstm_scan(
    const _Float16* __restrict__ P, const _Float16* __restrict__ Whh16,
    const int* __restrict__ lenp,
    _Float16* __restrict__ hseq,   // [2d][T][256][300]
    int T, int prow0)
{
  const int l = threadIdx.x & 63, w = threadIdx.x >> 6;
  const int bg = blockIdx.x, d = blockIdx.y;
  const int b0 = bg * 16;
  const int lrow = l & 15, lk = (l >> 4) * 8;
  const int mrow = l >> 4;

  __shared__ __align__(16) _Float16 Ah[16*328];  // h_{t-1}, pad stride 328
  __shared__ int lensh[16];

  for (int u = threadIdx.x; u < 16*328; u += 256) Ah[u] = (_Float16)0.f;
  if (threadIdx.x < 16) lensh[threadIdx.x] = lenp[b0 + threadIdx.x];
  __syncthreads();

  float cst[5][4];
  #pragma unroll
  for (int i = 0; i < 5; i++)
    #pragma unroll
    for (int r = 0; r < 4; r++) cst[i][r] = 0.f;

  for (int t = 0; t < T; t++) {
    // ---- prefetch P gate pre-activations for this step (hides under MFMA) ----
    float pre[5][4][4];   // [i][g][r]
    #pragma unroll
    for (int i = 0; i < 5; i++) {
      const int jt = w*5 + i;
      if (jt < 19) {
        const int jjv = jt*16 + lrow;   // may reach 303 (pad cols exist in P)
        #pragma unroll
        for (int r = 0; r < 4; r++) {
          const int m = mrow*4 + r;
          const int b = b0 + m;
          const int len = lensh[m];
          int teff;
          if (d == 0) teff = t;
          else { int v2 = len - 1 - t; teff = v2 < 0 ? 0 : (v2 > T-1 ? T-1 : v2); }
          const _Float16* Pr = P + (size_t)(prow0 + b*T + teff)*PPITCH + d*1216 + jjv;
          #pragma unroll
          for (int g = 0; g < 4; g++) pre[i][g][r] = (float)Pr[g*304];
        }
      }
    }

    // ---- MFMA phase: acc = h_{t-1} @ Whh^T (reads Ah) ----
    f32x4 acc[5][4];
    #pragma unroll
    for (int i = 0; i < 5; i++) {
      const int jt = w*5 + i;
      if (jt < 19) {
        #pragma unroll
        for (int g = 0; g < 4; g++) acc[i][g] = (f32x4){0.f,0.f,0.f,0.f};
        #pragma unroll
        for (int k0 = 0; k0 < 10; k0++) {
          half8 a = *(const half8*)&Ah[lrow*328 + k0*32 + lk];
          #pragma unroll
          for (int g = 0; g < 4; g++) {
            half8 bb = *(const half8*)(Whh16 +
                (size_t)(d*1216 + g*304 + jt*16 + lrow)*KP + k0*32 + lk);
            acc[i][g] = __builtin_amdgcn_mfma_f32_16x16x32_f16(a, bb, acc[i][g], 0, 0, 0);
          }
        }
      }
    }
    __syncthreads();   // all Ah reads done

    // ---- pointwise: gates in registers; update c (regs), h (Ah), hseq ----
    #pragma unroll
    for (int i = 0; i < 5; i++) {
      const int jt = w*5 + i;
      if (jt < 19) {
        const int jjv = jt*16 + lrow;
        const bool vv = jjv < NH;
        #pragma unroll
        for (int r = 0; r < 4; r++) {
          const int m = mrow*4 + r;
          const int b = b0 + m;
          const int len = lensh[m];
          float gi = acc[i][0][r] + pre[i][0][r];
          float gf = acc[i][1][r] + pre[i][1][r];
          float gg = acc[i][2][r] + pre[i][2][r];
          float go = acc[i][3][r] + pre[i][3][r];
          float cp = cst[i][r];
          float hp = vv ? (float)Ah[m*328 + jjv] : 0.f;
          float si = 1.f/(1.f + __expf(-gi));
          float sf = 1.f/(1.f + __expf(-gf));
          float so = 1.f/(1.f + __expf(-go));
          float cn = sf*cp + si*tanhf(gg);
          float hn = so*tanhf(cn);
          bool mt = t < len;
          float h2 = mt ? hn : hp;
          cst[i][r] = mt ? cn : cp;
          if (vv) {
            Ah[m*328 + jjv] = (_Float16)h2;
            hseq[(((size_t)d*T + t)*256 + b)*NH + jjv] = (_Float16)(mt ? hn : 0.f);
          }
        }
      }
    }
    __syncthreads();   // Ah writes done before next step's MFMA
  }
}

// ---------------- K3: combine + position weight -> ctx[b][s][600] ----------------
__global__ __launch_bounds__(320) void k_combine_ctx(
    const _Float16* __restrict__ hseq, const int* __restrict__ lens, _Float16* __restrict__ ctx)
{
  const int s = blockIdx.x, bg = blockIdx.y, tid = threadIdx.x;
  if (tid >= NH) return;
  for (int bq = 0; bq < 16; bq++) {
    int b = bg*16 + bq;
    int cl = lens[NB + b], ll = lens[b], al = lens[2*NB + b];
    float clf = (float)cl, llf = (float)ll, alf = (float)al;
    float tf = (float)s, denom = clf - alf + 1.f;
    float wgt = (tf < llf) ? (1.f - (llf - tf)/denom)
              : (tf < llf + alf) ? 0.f
              : (tf < clf) ? (1.f - (tf - llf - alf + 1.f)/denom) : 0.f;
    float vf = (float)hseq[((size_t)s*256 + b)*NH + tid];
    int tb0 = cl - 1 - s; int tb = tb0 < 0 ? 0 : (tb0 > NS-1 ? NS-1 : tb0);
    float vb = (s < cl) ? (float)hseq[((size_t)(NS + tb)*256 + b)*NH + tid] : 0.f;
    ctx[((size_t)b*NS + s)*600 + tid]      = (_Float16)(vf * wgt);
    ctx[((size_t)b*NS + s)*600 + NH + tid] = (_Float16)(vb * wgt);
  }
}

// ---------------- K3b: transpose ctx -> ctxT[b][j][s] ----------------
__global__ void k_transpose(const _Float16* __restrict__ ctx, _Float16* __restrict__ ctxT) {
  __shared__ _Float16 tl[32][34];
  int b = blockIdx.x, s0 = blockIdx.y*32, j0 = blockIdx.z*32;
  int c = threadIdx.x & 31, r0 = threadIdx.x >> 5;
  #pragma unroll
  for (int i = 0; i < 4; i++) {
    int r = r0 + i*8;
    int j = j0 + c;
    tl[r][c] = (j < 600) ? ctx[((long)b*NS + s0 + r)*600 + j] : (_Float16)0.f;
  }
  __syncthreads();
  #pragma unroll
  for (int i = 0; i < 4; i++) {
    int r = r0 + i*8;
    int j = j0 + r;
    if (j < 600) ctxT[((long)b*600 + j)*NS + s0 + c] = tl[c][r];
  }
}

// ---------------- K4: aspect combine -> aspc[b][a][600] ----------------
__global__ __launch_bounds__(320) void k_combine_asp(
    const _Float16* __restrict__ hseq, const int* __restrict__ lens, _Float16* __restrict__ aspc)
{
  int b = blockIdx.x, tid = threadIdx.x;
  if (tid >= NH) return;
  int al = lens[2*NB + b];
  for (int a = 0; a < NA; a++) {
    float vf = (float)hseq[((size_t)a*256 + b)*NH + tid];
    int tb0 = al - 1 - a; int tb = tb0 < 0 ? 0 : (tb0 > NA-1 ? NA-1 : tb0);
    float vb = (a < al) ? (float)hseq[((size_t)(NA + tb)*256 + b)*NH + tid] : 0.f;
    aspc[((size_t)b*NA + a)*600 + tid]      = (_Float16)vf;
    aspc[((size_t)b*NA + a)*600 + NH + tid] = (_Float16)vb;
  }
}

// ---------------- K5: c_avg, a_avg ----------------
__global__ void k_avg(const _Float16* __restrict__ ctx, const _Float16* __restrict__ aspc,
                      const int* __restrict__ lens, float* __restrict__ c_avg, float* __restrict__ a_avg) {
  int b = blockIdx.x, j = threadIdx.x;
  if (j >= 600) return;
  float ac = 0.f;
  for (int s = 0; s < NS; s++) ac += (float)ctx[((long)b*NS + s)*600 + j];
  c_avg[(long)b*600 + j] = ac / (float)lens[NB + b];
  float aa = 0.f;
  for (int a = 0; a < NA; a++) aa += (float)aspc[((long)b*NA + a)*600 + j];
  a_avg[(long)b*600 + j] = aa / (float)lens[2*NB + b];
}

// ---------------- K6: s1 = a_avg@w1 ; s2 = c_avg@w2 ----------------
__global__ void k_sw(const float* __restrict__ a_avg, const float* __restrict__ c_avg,
                     const float* __restrict__ w1, const float* __restrict__ w2,
                     float* __restrict__ s1, float* __restrict__ s2) {
  __shared__ float src[8][600];
  int bg = blockIdx.x * 8, which = blockIdx.y, tid = threadIdx.x;
  const float* sp = which ? c_avg : a_avg;
  const float* w  = which ? w2 : w1;
  float* outp     = which ? s2 : s1;
  for (int u = tid; u < 8*600; u += 640) {
    int q = u / 600, dd = u - q*600;
    src[q][dd] = sp[(long)(bg + q)*600 + dd];
  }
  __syncthreads();
  int j = tid;
  if (j >= 600) return;
  float acc[8] = {0,0,0,0,0,0,0,0};
  for (int dd = 0; dd < 600; dd++) {
    float wvv = w[dd*600 + j];
    #pragma unroll
    for (int q = 0; q < 8; q++) acc[q] += src[q][dd] * wvv;
  }
  #pragma unroll
  for (int q = 0; q < 8; q++) outp[(long)(bg + q)*600 + j] = acc[q];
}

// ---------------- K7: alpha1 + mca ----------------
__global__ __launch_bounds__(128) void k_att_ctx(const _Float16* __restrict__ ctxT,
    const _Float16* __restrict__ ctx, const float* __restrict__ s1, float* __restrict__ mca) {
  int b = blockIdx.x, tid = threadIdx.x;
  __shared__ float sv[600];
  __shared__ float red[128];
  __shared__ float mx, sm;
  for (int u = tid; u < 600; u += 128) sv[u] = s1[(long)b*600 + u];
  __syncthreads();
  float sc = 0.f;
  for (int dd = 0; dd < 600; dd++) sc += sv[dd] * (float)ctxT[((long)b*600 + dd)*NS + tid];
  red[tid] = sc; __syncthreads();
  if (tid == 0) { float m = -1e30f; for (int i = 0; i < 128; i++) m = fmaxf(m, red[i]); mx = m; }
  __syncthreads();
  float e = __expf(sc - mx);
  red[tid] = e; __syncthreads();
  if (tid == 0) { float s = 0.f; for (int i = 0; i < 128; i++) s += red[i]; sm = s; }
  __syncthreads();
  float alpha = e / sm;
  red[tid] = alpha; __syncthreads();
  for (int i = 0; i < 5; i++) {
    int j = tid + i*128;
    if (j < 600) {
      float acc = 0.f;
      for (int s2 = 0; s2 < NS; s2++) acc += red[s2] * (float)ctx[((long)b*NS + s2)*600 + j];
      mca[(long)b*600 + j] = acc;
    }
  }
}

// ---------------- K8: alpha2 + mcc ----------------
__global__ void k_att_asp(const _Float16* __restrict__ aspc, const float* __restrict__ s2,
                          float* __restrict__ mcc) {
  int b = blockIdx.x, tid = threadIdx.x, wvv = tid >> 6, lane = tid & 63;
  __shared__ float sv[600];
  __shared__ float sc8[8];
  for (int u = tid; u < 600; u += 512) sv[u] = s2[(long)b*600 + u];
  __syncthreads();
  float p = 0.f;
  for (int dd = lane; dd < 600; dd += 64) p += sv[dd] * (float)aspc[((long)b*NA + wvv)*600 + dd];
  #pragma unroll
  for (int off = 32; off; off >>= 1) p += __shfl_down(p, off);
  if (lane == 0) sc8[wvv] = p;
  __syncthreads();
  float m = -1e30f;
  #pragma unroll
  for (int a = 0; a < 8; a++) m = fmaxf(m, sc8[a]);
  float es[8]; float ssum = 0.f;
  #pragma unroll
  for (int a = 0; a < 8; a++) { es[a] = __expf(sc8[a] - m); ssum += es[a]; }
  float inv = 1.f / ssum;
  for (int i = 0; i < 2; i++) {
    int j = tid + i*512;
    if (j < 600) {
      float acc = 0.f;
      #pragma unroll
      for (int a = 0; a < 8; a++) acc += es[a]*inv * (float)aspc[((long)b*NA + a)*600 + j];
      mcc[(long)b*600 + j] = acc;
    }
  }
}

// ---------------- K9: u tensor -> mfa, mfc ----------------
__global__ __launch_bounds__(128) void k_u(const _Float16* __restrict__ ctxT, const _Float16* __restrict__ ctx,
    const _Float16* __restrict__ aspc, const float* __restrict__ fc1_w, const float* __restrict__ fc1_b,
    float* __restrict__ mfa, float* __restrict__ mfc) {
  int b = blockIdx.x, tid = threadIdx.x;   // tid == s
  __shared__ __align__(16) float aspl[4800];   // [d][a]
  __shared__ float ua8[8];
  __shared__ float red[128];
  __shared__ float qa8[8];
  __shared__ float mx1, sm1;
  __shared__ float pal[128][8];
  for (int u = tid; u < 4800; u += 128) {
    int a = u / 600, dd = u - a*600;
    aspl[dd*8 + a] = (float)aspc[((long)b*NA + a)*600 + dd];
  }
  __syncthreads();
  const float* wc = fc1_w;
  const float* wa = fc1_w + 600;
  const float* wm = fc1_w + 1200;
  {
    int wvv = tid >> 6, lane = tid & 63;
    for (int q = 0; q < 4; q++) {
      int a = wvv*4 + q;
      float p = 0.f;
      for (int dd = lane; dd < 600; dd += 64) p += wa[dd] * aspl[dd*8 + a];
      #pragma unroll
      for (int off = 32; off; off >>= 1) p += __shfl_down(p, off);
      if (lane == 0) ua8[a] = p;
    }
  }
  __syncthreads();
  float x8[8] = {0,0,0,0,0,0,0,0};
  float uc = 0.f;
  for (int dd = 0; dd < 600; dd++) {
    float cv = (float)ctxT[((long)b*600 + dd)*NS + tid];
    uc += cv * wc[dd];
    float cm = cv * wm[dd];
    float4 a03 = *(const float4*)&aspl[dd*8];
    float4 a47 = *(const float4*)&aspl[dd*8 + 4];
    x8[0] += cm*a03.x; x8[1] += cm*a03.y; x8[2] += cm*a03.z; x8[3] += cm*a03.w;
    x8[4] += cm*a47.x; x8[5] += cm*a47.y; x8[6] += cm*a47.z; x8[7] += cm*a47.w;
  }
  float fb = fc1_b[0];
  float u8v[8]; float umax = -1e30f;
  #pragma unroll
  for (int a = 0; a < 8; a++) { u8v[a] = uc + ua8[a] + x8[a] + fb; umax = fmaxf(umax, u8v[a]); }
  float pa[8]; float psum = 0.f;
  #pragma unroll
  for (int a = 0; a < 8; a++) { pa[a] = __expf(u8v[a] - umax); psum += pa[a]; }
  float pin = 1.f / psum;
  #pragma unroll
  for (int a = 0; a < 8; a++) pal[tid][a] = pa[a] * pin;
  red[tid] = umax;
  __syncthreads();
  if (tid == 0) { float m = -1e30f; for (int i = 0; i < 128; i++) m = fmaxf(m, red[i]); mx1 = m; }
  if (tid < 8) { float s = 0.f; for (int i = 0; i < 128; i++) s += pal[i][tid]; qa8[tid] = s * (1.f/128.f); }
  __syncthreads();
  float e = __expf(umax - mx1);
  red[tid] = e;
  __syncthreads();
  if (tid == 0) { float s = 0.f; for (int i = 0; i < 128; i++) s += red[i]; sm1 = s; }
  __syncthreads();
  float alpha = e / sm1;
  red[tid] = alpha;
  __syncthreads();
  for (int i = 0; i < 5; i++) {
    int j = tid + i*128;
    if (j < 600) {
      float am = 0.f;
      for (int s2 = 0; s2 < NS; s2++) am += red[s2] * (float)ctx[((long)b*NS + s2)*600 + j];
      float4 a03 = *(const float4*)&aspl[j*8];
      float4 a47 = *(const float4*)&aspl[j*8 + 4];
      mfa[(long)b*600 + j] = am;
      mfc[(long)b*600 + j] = qa8[0]*a03.x + qa8[1]*a03.y + qa8[2]*a03.z + qa8[3]*a03.w
                           + qa8[4]*a47.x + qa8[5]*a47.y + qa8[6]*a47.z + qa8[7]*a47.w;
    }
  }
}

// ---------------- K10: final FC + softmax ----------------
__global__ void k_final(const float* __restrict__ mca, const float* __restrict__ mcc,
                        const float* __restrict__ mfa, const float* __restrict__ mfc,
                        const float* __restrict__ fc2_w, const float* __restrict__ fc2_b,
                        float* __restrict__ out) {
  int b = blockIdx.x, tid = threadIdx.x, c = tid >> 6, lane = tid & 63;
  __shared__ float lg[3];
  float p = 0.f;
  for (int u = lane; u < 2400; u += 64) {
    int piece = u / 600;
    int jj = u - piece*600;
    const float* src = (piece == 0) ? mca : (piece == 1) ? mcc : (piece == 2) ? mfa : mfc;
    p += src[(long)b*600 + jj] * fc2_w[c*2400 + u];
  }
  #pragma unroll
  for (int off = 32; off; off >>= 1) p += __shfl_down(p, off);
  if (lane == 0) lg[c] = p + fc2_b[c];
  __syncthreads();
  if (tid == 0) {
    float m = fmaxf(lg[0], fmaxf(lg[1], lg[2]));
    float e0 = __expf(lg[0]-m), e1 = __expf(lg[1]-m), e2 = __expf(lg[2]-m);
    float s = e0 + e1 + e2;
    out[b*3 + 0] = e0/s; out[b*3 + 1] = e1/s; out[b*3 + 2] = e2/s;
  }
}

// ---------------- host ----------------
extern "C" void kernel_launch(void* const* d_in, const int* in_sizes, int n_in,
                              void* d_out, int out_size, void* d_ws, size_t ws_size,
                              hipStream_t stream)
{
  const int*   text    = (const int*)d_in[0];
  const int*   aspect  = (const int*)d_in[1];
  const int*   left    = (const int*)d_in[2];
  const float* emb     = (const float*)d_in[3];
  const float* Wih_f   = (const float*)d_in[4];
  const float* Whh_f   = (const float*)d_in[5];
  const float* bih_f   = (const float*)d_in[6];
  const float* bhh_f   = (const float*)d_in[7];
  const float* Wih_b   = (const float*)d_in[8];
  const float* Whh_b   = (const float*)d_in[9];
  const float* bih_b   = (const float*)d_in[10];
  const float* bhh_b   = (const float*)d_in[11];
  const float* w1      = (const float*)d_in[12];
  const float* w2      = (const float*)d_in[13];
  const float* fc1_w   = (const float*)d_in[14];
  const float* fc1_b   = (const float*)d_in[15];
  const float* fc2_w   = (const float*)d_in[16];
  const float* fc2_b   = (const float*)d_in[17];
  float* out = (float*)d_out;

  char* base = (char*)d_ws;
  size_t off = 0;
  auto alloc = [&](size_t bytes) -> void* {
    void* p = base + off;
    off = (off + bytes + 255) & ~(size_t)255;
    return p;
  };
  int*      lens     = (int*)     alloc(3 * NB * sizeof(int));
  float*    bias_sum = (float*)   alloc(NPAD * sizeof(float));
  _Float16* Wih16    = (_Float16*)alloc((size_t)NPAD*KP * sizeof(_Float16));     // 1.56 MB
  _Float16* Whh16    = (_Float16*)alloc((size_t)NPAD*KP * sizeof(_Float16));     // 1.56 MB
  float*    c_avg    = (float*)   alloc((size_t)NB*600 * sizeof(float));
  float*    a_avg    = (float*)   alloc((size_t)NB*600 * sizeof(float));
  float*    s1       = (float*)   alloc((size_t)NB*600 * sizeof(float));
  float*    s2       = (float*)   alloc((size_t)NB*600 * sizeof(float));
  float*    mca      = (float*)   alloc((size_t)NB*600 * sizeof(float));
  float*    mcc      = (float*)   alloc((size_t)NB*600 * sizeof(float));
  float*    mfa      = (float*)   alloc((size_t)NB*600 * sizeof(float));
  float*    mfc      = (float*)   alloc((size_t)NB*600 * sizeof(float));
  // hseqC region (39.3 MB) doubles as emb16 (20.5 MB) before the scans
  _Float16* hseqC    = (_Float16*)alloc((size_t)2*NS*NB*NH * sizeof(_Float16));
  _Float16* emb16    = hseqC;
  _Float16* hseqA    = (_Float16*)alloc((size_t)2*NA*NB*NH * sizeof(_Float16));  // 2.46 MB
  // BIG region: padded P (169 MB), overlaid later by ctx/ctxT/aspc (81 MB)
  char* bigBase = (char*)alloc((size_t)TOK_ALL * PPITCH * sizeof(_Float16));
  _Float16* P    = (_Float16*)bigBase;
  _Float16* ctx  = (_Float16*)bigBase;
  _Float16* ctxT = ctx  + (size_t)NB*NS*600;
  _Float16* aspc = ctxT + (size_t)NB*NS*600;
  if (ws_size < off) return;  // clean zero-output signal instead of OOB

  k_lengths<<<1, 256, 0, stream>>>(text, aspect, left, lens);
  k_cvt_emb<<<2048, 256, 0, stream>>>(emb, emb16);
  k_cvt_w<<<dim3(512, 3), 256, 0, stream>>>(Wih_f, Wih_b, Whh_f, Whh_b,
                                            bih_f, bhh_f, bih_b, bhh_b,
                                            Wih16, Whh16, bias_sum);
  k_inproj<<<dim3(272, 19), 256, 0, stream>>>(emb16, text, aspect, Wih16, bias_sum, P);

  k_lstm_scan<<<dim3(16, 2), 256, 0, stream>>>(P, Whh16, lens + NB,   hseqC, NS, 0);
  k_lstm_scan<<<dim3(16, 2), 256, 0, stream>>>(P, Whh16, lens + 2*NB, hseqA, NA, TOK_CTX);

  k_combine_ctx<<<dim3(128, 16), 320, 0, stream>>>(hseqC, lens, ctx);
  k_transpose<<<dim3(256, 4, 19), 256, 0, stream>>>(ctx, ctxT);
  k_combine_asp<<<256, 320, 0, stream>>>(hseqA, lens, aspc);
  k_avg<<<256, 640, 0, stream>>>(ctx, aspc, lens, c_avg, a_avg);
  k_sw<<<dim3(32, 2), 640, 0, stream>>>(a_avg, c_avg, w1, w2, s1, s2);
  k_att_ctx<<<256, 128, 0, stream>>>(ctxT, ctx, s1, mca);
  k_att_asp<<<256, 512, 0, stream>>>(aspc, s2, mcc);
  k_u<<<256, 128, 0, stream>>>(ctxT, ctx, aspc, fc1_w, fc1_b, mfa, mfc);
  k_final<<<256, 192, 0, stream>>>(mca, mcc, mfa, mfc, fc2_w, fc2_b, out);
}

// Round 7
// 4122.802 us; speedup vs baseline: 1.1277x; 1.1277x over previous
//
#include <hip/hip_runtime.h>
#include <hip/hip_bf16.h>
#include <hip/hip_fp16.h>

// ---------------------------------------------------------------------------
// MGAN forward. fp16 MFMA; block-local LSTM scan (NO cross-block sync).
//   B=256 S=128 A=8 L=32 D=H=300 NC=3 VOCAB=32000
// MFMA 16x16x32_f16 fragment scheme (validated rounds 2-3,6):
//   A-frag: lane holds A[m = l&15][k = (l>>4)*8 + j]
//   B-frag (B^T [n][k]): lane holds B[n = l&15][k = (l>>4)*8 + j]
//   D:      lane,reg r -> D[m = (l>>4)*4 + r][n = l&15]
// P PADDED: pitch 2432 = [dir 2][gate 4][304], K padded 300->320.
// Scan (round 7): SAME math/indexing as validated round 6, but 1024 threads
// = 16 waves/block (4/SIMD -> latency hiding), <=2 jt-tiles per wave
// (reg-light, no spills), ctx+asp scans merged into one launch (grid z).
// ---------------------------------------------------------------------------

#define NB   256
#define NS   128
#define NA   8
#define NL   32
#define ND   300
#define NH   300
#define NPAD  2432      // 2*4*304
#define PPITCH 2432
#define KP    320
#define TOK_CTX 32768
#define TOK_ALL 34816

typedef _Float16 half8 __attribute__((ext_vector_type(8)));
typedef float    f32x4 __attribute__((ext_vector_type(4)));

// ---------------- K0: sequence lengths ----------------
__global__ void k_lengths(const int* __restrict__ text, const int* __restrict__ aspect,
                          const int* __restrict__ left, int* __restrict__ lens) {
  int b = threadIdx.x;
  if (b >= NB) return;
  int ll = 0; for (int i = 0; i < NL; i++) ll += (left[b*NL + i] != 0);
  int cl = 0; for (int i = 0; i < NS; i++) cl += (text[b*NS + i] != 0);
  int al = 0; for (int i = 0; i < NA; i++) al += (aspect[b*NA + i] != 0);
  lens[b] = ll; lens[NB + b] = cl; lens[2*NB + b] = al;
}

// ---------------- converters ----------------
__global__ void k_cvt_emb(const float* __restrict__ emb, _Float16* __restrict__ emb16) {
  const long N = (long)32000 * KP;
  for (long i = (long)blockIdx.x*blockDim.x + threadIdx.x; i < N; i += (long)gridDim.x*blockDim.x) {
    long v = i / KP; int k = (int)(i - v*KP);
    emb16[i] = (k < ND) ? (_Float16)emb[v*ND + k] : (_Float16)0.f;
  }
}

// y==0: Wih16, y==1: Whh16, y==2: bias_sum  (layout [d][g][304][320], zero pad)
__global__ void k_cvt_w(const float* __restrict__ Wih_f, const float* __restrict__ Wih_b,
                        const float* __restrict__ Whh_f, const float* __restrict__ Whh_b,
                        const float* __restrict__ bih_f, const float* __restrict__ bhh_f,
                        const float* __restrict__ bih_b, const float* __restrict__ bhh_b,
                        _Float16* __restrict__ Wih16, _Float16* __restrict__ Whh16,
                        float* __restrict__ bias_sum) {
  int y = blockIdx.y;
  if (y < 2) {
    const long N = (long)NPAD * KP;
    const float* sf = y ? Whh_f : Wih_f;
    const float* sb = y ? Whh_b : Wih_b;
    _Float16* dst = y ? Whh16 : Wih16;
    for (long i = (long)blockIdx.x*blockDim.x + threadIdx.x; i < N; i += (long)gridDim.x*blockDim.x) {
      long row = i / KP; int k = (int)(i - row*KP);
      int d = (int)(row / 1216); int rem = (int)(row - (long)d*1216);
      int g = rem / 304; int jj = rem - g*304;
      float v = 0.f;
      if (jj < NH && k < NH) {
        const float* src = d ? sb : sf;
        v = src[(long)(g*NH + jj)*NH + k];
      }
      dst[i] = (_Float16)v;
    }
  } else {
    for (int i = blockIdx.x*blockDim.x + threadIdx.x; i < NPAD; i += gridDim.x*blockDim.x) {
      int d = i / 1216; int rem = i - d*1216;
      int g = rem / 304; int jj = rem - g*304;
      float v = 0.f;
      if (jj < NH) {
        v = d ? (bih_b[g*NH + jj] + bhh_b[g*NH + jj]) : (bih_f[g*NH + jj] + bhh_f[g*NH + jj]);
      }
      bias_sum[i] = v;
    }
  }
}

// ---------------- K1: input projection GEMM via MFMA, LDS-coalesced epilogue ----
__global__ __launch_bounds__(256) void k_inproj(
    const _Float16* __restrict__ emb16, const int* __restrict__ text, const int* __restrict__ aspect,
    const _Float16* __restrict__ Wih16, const float* __restrict__ bias_sum,
    _Float16* __restrict__ P)
{
  const int l = threadIdx.x & 63, w = threadIdx.x >> 6;
  const int m0 = blockIdx.x * 128, n0 = blockIdx.y * 128;
  const int lrow = l & 15, lk = (l >> 4) * 8;
  __shared__ __align__(16) _Float16 Cs[128*136];

  const _Float16* ap[2];
  #pragma unroll
  for (int q = 0; q < 2; q++) {
    int r = m0 + (2*w + q)*16 + lrow;
    int tok = (r < TOK_CTX) ? text[r] : aspect[r - TOK_CTX];
    ap[q] = emb16 + (long)tok*KP + lk;
  }
  const _Float16* bp[8];
  #pragma unroll
  for (int nt = 0; nt < 8; nt++)
    bp[nt] = Wih16 + (long)(n0 + nt*16 + lrow)*KP + lk;

  f32x4 acc[2][8];
  #pragma unroll
  for (int q = 0; q < 2; q++)
    #pragma unroll
    for (int nt = 0; nt < 8; nt++) acc[q][nt] = (f32x4){0.f,0.f,0.f,0.f};

  #pragma unroll
  for (int k0 = 0; k0 < 10; k0++) {
    half8 a0 = *(const half8*)(ap[0] + k0*32);
    half8 a1 = *(const half8*)(ap[1] + k0*32);
    #pragma unroll
    for (int nt = 0; nt < 8; nt++) {
      half8 bb = *(const half8*)(bp[nt] + k0*32);
      acc[0][nt] = __builtin_amdgcn_mfma_f32_16x16x32_f16(a0, bb, acc[0][nt], 0, 0, 0);
      acc[1][nt] = __builtin_amdgcn_mfma_f32_16x16x32_f16(a1, bb, acc[1][nt], 0, 0, 0);
    }
  }

  #pragma unroll
  for (int nt = 0; nt < 8; nt++) {
    float bias = bias_sum[n0 + nt*16 + lrow];
    #pragma unroll
    for (int q = 0; q < 2; q++) {
      int lr = (2*w + q)*16 + (l>>4)*4;
      #pragma unroll
      for (int r = 0; r < 4; r++)
        Cs[(lr + r)*136 + nt*16 + lrow] = (_Float16)(acc[q][nt][r] + bias);
    }
  }
  __syncthreads();
  const int row = threadIdx.x >> 1, ch = (threadIdx.x & 1)*64;
  long gbase = (long)(m0 + row)*PPITCH + n0 + ch;
  #pragma unroll
  for (int i = 0; i < 8; i++) {
    half8 v = *(const half8*)&Cs[row*136 + ch + i*8];
    *(half8*)&P[gbase + i*8] = v;
  }
}

// ---------------- K2: block-local LSTM scan, 16 waves/block ----------------
// grid (16 bg, 2 d, 2 which), 1024 thr = 16 waves. Wave w owns jt in {w, w+16}.
__global__ __launch_bounds__(1024, 1) void k_lstm_scan(
    const _Float16* __restrict__ P, const _Float16* __restrict__ Whh16,
    const int* __restrict__ lens,
    _Float16* __restrict__ hseqC, _Float16* __restrict__ hseqA)
{
  const int l = threadIdx.x & 63, w = threadIdx.x >> 6;
  const int bg = blockIdx.x, d = blockIdx.y, which = blockIdx.z;
  const int T = which ? NA : NS;
  const int prow0 = which ? TOK_CTX : 0;
  const int* __restrict__ lenp = lens + (which ? 2*NB : NB);
  _Float16* __restrict__ hseq = which ? hseqA : hseqC;
  const int b0 = bg * 16;
  const int lrow = l & 15, lk = (l >> 4) * 8;
  const int mrow = l >> 4;

  __shared__ __align__(16) _Float16 Ah[16*328];  // h_{t-1}, pad stride 328
  __shared__ int lensh[16];

  for (int u = threadIdx.x; u < 16*328; u += 1024) Ah[u] = (_Float16)0.f;
  if (threadIdx.x < 16) lensh[threadIdx.x] = lenp[b0 + threadIdx.x];
  __syncthreads();

  float cst[2][4];
  #pragma unroll
  for (int i = 0; i < 2; i++)
    #pragma unroll
    for (int r = 0; r < 4; r++) cst[i][r] = 0.f;

  for (int t = 0; t < T; t++) {
    // ---- prefetch P gate pre-activations for this step (hides under MFMA) ----
    float pre[2][4][4];   // [i][g][r]
    #pragma unroll
    for (int i = 0; i < 2; i++) {
      const int jt = w + 16*i;
      if (jt < 19) {
        const int jjv = jt*16 + lrow;   // may reach 303 (pad cols exist in P)
        #pragma unroll
        for (int r = 0; r < 4; r++) {
          const int m = mrow*4 + r;
          const int b = b0 + m;
          const int len = lensh[m];
          int teff;
          if (d == 0) teff = t;
          else { int v2 = len - 1 - t; teff = v2 < 0 ? 0 : (v2 > T-1 ? T-1 : v2); }
          const _Float16* Pr = P + (size_t)(prow0 + b*T + teff)*PPITCH + d*1216 + jjv;
          #pragma unroll
          for (int g = 0; g < 4; g++) pre[i][g][r] = (float)Pr[g*304];
        }
      }
    }

    // ---- MFMA phase: acc = h_{t-1} @ Whh^T (reads Ah; t=0 -> Ah=0 -> acc=0) ----
    f32x4 acc[2][4];
    #pragma unroll
    for (int i = 0; i < 2; i++) {
      const int jt = w + 16*i;
      if (jt < 19) {
        #pragma unroll
        for (int g = 0; g < 4; g++) acc[i][g] = (f32x4){0.f,0.f,0.f,0.f};
        #pragma unroll
        for (int k0 = 0; k0 < 10; k0++) {
          half8 a = *(const half8*)&Ah[lrow*328 + k0*32 + lk];
          #pragma unroll
          for (int g = 0; g < 4; g++) {
            half8 bb = *(const half8*)(Whh16 +
                (size_t)(d*1216 + g*304 + jt*16 + lrow)*KP + k0*32 + lk);
            acc[i][g] = __builtin_amdgcn_mfma_f32_16x16x32_f16(a, bb, acc[i][g], 0, 0, 0);
          }
        }
      }
    }
    __syncthreads();   // all Ah reads done

    // ---- pointwise: gates in registers; update c (regs), h (Ah), hseq ----
    #pragma unroll
    for (int i = 0; i < 2; i++) {
      const int jt = w + 16*i;
      if (jt < 19) {
        const int jjv = jt*16 + lrow;
        const bool vv = jjv < NH;
        #pragma unroll
        for (int r = 0; r < 4; r++) {
          const int m = mrow*4 + r;
          const int b = b0 + m;
          const int len = lensh[m];
          float gi = acc[i][0][r] + pre[i][0][r];
          float gf = acc[i][1][r] + pre[i][1][r];
          float gg = acc[i][2][r] + pre[i][2][r];
          float go = acc[i][3][r] + pre[i][3][r];
          float cp = cst[i][r];
          float hp = vv ? (float)Ah[m*328 + jjv] : 0.f;
          float si = 1.f/(1.f + __expf(-gi));
          float sf = 1.f/(1.f + __expf(-gf));
          float so = 1.f/(1.f + __expf(-go));
          float cn = sf*cp + si*tanhf(gg);
          float hn = so*tanhf(cn);
          bool mt = t < len;
          float h2 = mt ? hn : hp;
          cst[i][r] = mt ? cn : cp;
          if (vv) {
            Ah[m*328 + jjv] = (_Float16)h2;
            hseq[(((size_t)d*T + t)*256 + b)*NH + jjv] = (_Float16)(mt ? hn : 0.f);
          }
        }
      }
    }
    __syncthreads();   // Ah writes done before next step's MFMA
  }
}

// ---------------- K3: combine + position weight -> ctx[b][s][600] ----------------
__global__ __launch_bounds__(320) void k_combine_ctx(
    const _Float16* __restrict__ hseq, const int* __restrict__ lens, _Float16* __restrict__ ctx)
{
  const int s = blockIdx.x, bg = blockIdx.y, tid = threadIdx.x;
  if (tid >= NH) return;
  for (int bq = 0; bq < 16; bq++) {
    int b = bg*16 + bq;
    int cl = lens[NB + b], ll = lens[b], al = lens[2*NB + b];
    float clf = (float)cl, llf = (float)ll, alf = (float)al;
    float tf = (float)s, denom = clf - alf + 1.f;
    float wgt = (tf < llf) ? (1.f - (llf - tf)/denom)
              : (tf < llf + alf) ? 0.f
              : (tf < clf) ? (1.f - (tf - llf - alf + 1.f)/denom) : 0.f;
    float vf = (float)hseq[((size_t)s*256 + b)*NH + tid];
    int tb0 = cl - 1 - s; int tb = tb0 < 0 ? 0 : (tb0 > NS-1 ? NS-1 : tb0);
    float vb = (s < cl) ? (float)hseq[((size_t)(NS + tb)*256 + b)*NH + tid] : 0.f;
    ctx[((size_t)b*NS + s)*600 + tid]      = (_Float16)(vf * wgt);
    ctx[((size_t)b*NS + s)*600 + NH + tid] = (_Float16)(vb * wgt);
  }
}

// ---------------- K3b: transpose ctx -> ctxT[b][j][s] ----------------
__global__ void k_transpose(const _Float16* __restrict__ ctx, _Float16* __restrict__ ctxT) {
  __shared__ _Float16 tl[32][34];
  int b = blockIdx.x, s0 = blockIdx.y*32, j0 = blockIdx.z*32;
  int c = threadIdx.x & 31, r0 = threadIdx.x >> 5;
  #pragma unroll
  for (int i = 0; i < 4; i++) {
    int r = r0 + i*8;
    int j = j0 + c;
    tl[r][c] = (j < 600) ? ctx[((long)b*NS + s0 + r)*600 + j] : (_Float16)0.f;
  }
  __syncthreads();
  #pragma unroll
  for (int i = 0; i < 4; i++) {
    int r = r0 + i*8;
    int j = j0 + r;
    if (j < 600) ctxT[((long)b*600 + j)*NS + s0 + c] = tl[c][r];
  }
}

// ---------------- K4: aspect combine -> aspc[b][a][600] ----------------
__global__ __launch_bounds__(320) void k_combine_asp(
    const _Float16* __restrict__ hseq, const int* __restrict__ lens, _Float16* __restrict__ aspc)
{
  int b = blockIdx.x, tid = threadIdx.x;
  if (tid >= NH) return;
  int al = lens[2*NB + b];
  for (int a = 0; a < NA; a++) {
    float vf = (float)hseq[((size_t)a*256 + b)*NH + tid];
    int tb0 = al - 1 - a; int tb = tb0 < 0 ? 0 : (tb0 > NA-1 ? NA-1 : tb0);
    float vb = (a < al) ? (float)hseq[((size_t)(NA + tb)*256 + b)*NH + tid] : 0.f;
    aspc[((size_t)b*NA + a)*600 + tid]      = (_Float16)vf;
    aspc[((size_t)b*NA + a)*600 + NH + tid] = (_Float16)vb;
  }
}

// ---------------- K5: c_avg, a_avg ----------------
__global__ void k_avg(const _Float16* __restrict__ ctx, const _Float16* __restrict__ aspc,
                      const int* __restrict__ lens, float* __restrict__ c_avg, float* __restrict__ a_avg) {
  int b = blockIdx.x, j = threadIdx.x;
  if (j >= 600) return;
  float ac = 0.f;
  for (int s = 0; s < NS; s++) ac += (float)ctx[((long)b*NS + s)*600 + j];
  c_avg[(long)b*600 + j] = ac / (float)lens[NB + b];
  float aa = 0.f;
  for (int a = 0; a < NA; a++) aa += (float)aspc[((long)b*NA + a)*600 + j];
  a_avg[(long)b*600 + j] = aa / (float)lens[2*NB + b];
}

// ---------------- K6: s1 = a_avg@w1 ; s2 = c_avg@w2 ----------------
__global__ void k_sw(const float* __restrict__ a_avg, const float* __restrict__ c_avg,
                     const float* __restrict__ w1, const float* __restrict__ w2,
                     float* __restrict__ s1, float* __restrict__ s2) {
  __shared__ float src[8][600];
  int bg = blockIdx.x * 8, which = blockIdx.y, tid = threadIdx.x;
  const float* sp = which ? c_avg : a_avg;
  const float* w  = which ? w2 : w1;
  float* outp     = which ? s2 : s1;
  for (int u = tid; u < 8*600; u += 640) {
    int q = u / 600, dd = u - q*600;
    src[q][dd] = sp[(long)(bg + q)*600 + dd];
  }
  __syncthreads();
  int j = tid;
  if (j >= 600) return;
  float acc[8] = {0,0,0,0,0,0,0,0};
  for (int dd = 0; dd < 600; dd++) {
    float wvv = w[dd*600 + j];
    #pragma unroll
    for (int q = 0; q < 8; q++) acc[q] += src[q][dd] * wvv;
  }
  #pragma unroll
  for (int q = 0; q < 8; q++) outp[(long)(bg + q)*600 + j] = acc[q];
}

// ---------------- K7: alpha1 + mca ----------------
__global__ __launch_bounds__(128) void k_att_ctx(const _Float16* __restrict__ ctxT,
    const _Float16* __restrict__ ctx, const float* __restrict__ s1, float* __restrict__ mca) {
  int b = blockIdx.x, tid = threadIdx.x;
  __shared__ float sv[600];
  __shared__ float red[128];
  __shared__ float mx, sm;
  for (int u = tid; u < 600; u += 128) sv[u] = s1[(long)b*600 + u];
  __syncthreads();
  float sc = 0.f;
  for (int dd = 0; dd < 600; dd++) sc += sv[dd] * (float)ctxT[((long)b*600 + dd)*NS + tid];
  red[tid] = sc; __syncthreads();
  if (tid == 0) { float m = -1e30f; for (int i = 0; i < 128; i++) m = fmaxf(m, red[i]); mx = m; }
  __syncthreads();
  float e = __expf(sc - mx);
  red[tid] = e; __syncthreads();
  if (tid == 0) { float s = 0.f; for (int i = 0; i < 128; i++) s += red[i]; sm = s; }
  __syncthreads();
  float alpha = e / sm;
  red[tid] = alpha; __syncthreads();
  for (int i = 0; i < 5; i++) {
    int j = tid + i*128;
    if (j < 600) {
      float acc = 0.f;
      for (int s2 = 0; s2 < NS; s2++) acc += red[s2] * (float)ctx[((long)b*NS + s2)*600 + j];
      mca[(long)b*600 + j] = acc;
    }
  }
}

// ---------------- K8: alpha2 + mcc ----------------
__global__ void k_att_asp(const _Float16* __restrict__ aspc, const float* __restrict__ s2,
                          float* __restrict__ mcc) {
  int b = blockIdx.x, tid = threadIdx.x, wvv = tid >> 6, lane = tid & 63;
  __shared__ float sv[600];
  __shared__ float sc8[8];
  for (int u = tid; u < 600; u += 512) sv[u] = s2[(long)b*600 + u];
  __syncthreads();
  float p = 0.f;
  for (int dd = lane; dd < 600; dd += 64) p += sv[dd] * (float)aspc[((long)b*NA + wvv)*600 + dd];
  #pragma unroll
  for (int off = 32; off; off >>= 1) p += __shfl_down(p, off);
  if (lane == 0) sc8[wvv] = p;
  __syncthreads();
  float m = -1e30f;
  #pragma unroll
  for (int a = 0; a < 8; a++) m = fmaxf(m, sc8[a]);
  float es[8]; float ssum = 0.f;
  #pragma unroll
  for (int a = 0; a < 8; a++) { es[a] = __expf(sc8[a] - m); ssum += es[a]; }
  float inv = 1.f / ssum;
  for (int i = 0; i < 2; i++) {
    int j = tid + i*512;
    if (j < 600) {
      float acc = 0.f;
      #pragma unroll
      for (int a = 0; a < 8; a++) acc += es[a]*inv * (float)aspc[((long)b*NA + a)*600 + j];
      mcc[(long)b*600 + j] = acc;
    }
  }
}

// ---------------- K9: u tensor -> mfa, mfc ----------------
__global__ __launch_bounds__(128) void k_u(const _Float16* __restrict__ ctxT, const _Float16* __restrict__ ctx,
    const _Float16* __restrict__ aspc, const float* __restrict__ fc1_w, const float* __restrict__ fc1_b,
    float* __restrict__ mfa, float* __restrict__ mfc) {
  int b = blockIdx.x, tid = threadIdx.x;   // tid == s
  __shared__ __align__(16) float aspl[4800];   // [d][a]
  __shared__ float ua8[8];
  __shared__ float red[128];
  __shared__ float qa8[8];
  __shared__ float mx1, sm1;
  __shared__ float pal[128][8];
  for (int u = tid; u < 4800; u += 128) {
    int a = u / 600, dd = u - a*600;
    aspl[dd*8 + a] = (float)aspc[((long)b*NA + a)*600 + dd];
  }
  __syncthreads();
  const float* wc = fc1_w;
  const float* wa = fc1_w + 600;
  const float* wm = fc1_w + 1200;
  {
    int wvv = tid >> 6, lane = tid & 63;
    for (int q = 0; q < 4; q++) {
      int a = wvv*4 + q;
      float p = 0.f;
      for (int dd = lane; dd < 600; dd += 64) p += wa[dd] * aspl[dd*8 + a];
      #pragma unroll
      for (int off = 32; off; off >>= 1) p += __shfl_down(p, off);
      if (lane == 0) ua8[a] = p;
    }
  }
  __syncthreads();
  float x8[8] = {0,0,0,0,0,0,0,0};
  float uc = 0.f;
  for (int dd = 0; dd < 600; dd++) {
    float cv = (float)ctxT[((long)b*600 + dd)*NS + tid];
    uc += cv * wc[dd];
    float cm = cv * wm[dd];
    float4 a03 = *(const float4*)&aspl[dd*8];
    float4 a47 = *(const float4*)&aspl[dd*8 + 4];
    x8[0] += cm*a03.x; x8[1] += cm*a03.y; x8[2] += cm*a03.z; x8[3] += cm*a03.w;
    x8[4] += cm*a47.x; x8[5] += cm*a47.y; x8[6] += cm*a47.z; x8[7] += cm*a47.w;
  }
  float fb = fc1_b[0];
  float u8v[8]; float umax = -1e30f;
  #pragma unroll
  for (int a = 0; a < 8; a++) { u8v[a] = uc + ua8[a] + x8[a] + fb; umax = fmaxf(umax, u8v[a]); }
  float pa[8]; float psum = 0.f;
  #pragma unroll
  for (int a = 0; a < 8; a++) { pa[a] = __expf(u8v[a] - umax); psum += pa[a]; }
  float pin = 1.f / psum;
  #pragma unroll
  for (int a = 0; a < 8; a++) pal[tid][a] = pa[a] * pin;
  red[tid] = umax;
  __syncthreads();
  if (tid == 0) { float m = -1e30f; for (int i = 0; i < 128; i++) m = fmaxf(m, red[i]); mx1 = m; }
  if (tid < 8) { float s = 0.f; for (int i = 0; i < 128; i++) s += pal[i][tid]; qa8[tid] = s * (1.f/128.f); }
  __syncthreads();
  float e = __expf(umax - mx1);
  red[tid] = e;
  __syncthreads();
  if (tid == 0) { float s = 0.f; for (int i = 0; i < 128; i++) s += red[i]; sm1 = s; }
  __syncthreads();
  float alpha = e / sm1;
  red[tid] = alpha;
  __syncthreads();
  for (int i = 0; i < 5; i++) {
    int j = tid + i*128;
    if (j < 600) {
      float am = 0.f;
      for (int s2 = 0; s2 < NS; s2++) am += red[s2] * (float)ctx[((long)b*NS + s2)*600 + j];
      float4 a03 = *(const float4*)&aspl[j*8];
      float4 a47 = *(const float4*)&aspl[j*8 + 4];
      mfa[(long)b*600 + j] = am;
      mfc[(long)b*600 + j] = qa8[0]*a03.x + qa8[1]*a03.y + qa8[2]*a03.z + qa8[3]*a03.w
                           + qa8[4]*a47.x + qa8[5]*a47.y + qa8[6]*a47.z + qa8[7]*a47.w;
    }
  }
}

// ---------------- K10: final FC + softmax ----------------
__global__ void k_final(const float* __restrict__ mca, const float* __restrict__ mcc,
                        const float* __restrict__ mfa, const float* __restrict__ mfc,
                        const float* __restrict__ fc2_w, const float* __restrict__ fc2_b,
                        float* __restrict__ out) {
  int b = blockIdx.x, tid = threadIdx.x, c = tid >> 6, lane = tid & 63;
  __shared__ float lg[3];
  float p = 0.f;
  for (int u = lane; u < 2400; u += 64) {
    int piece = u / 600;
    int jj = u - piece*600;
    const float* src = (piece == 0) ? mca : (piece == 1) ? mcc : (piece == 2) ? mfa : mfc;
    p += src[(long)b*600 + jj] * fc2_w[c*2400 + u];
  }
  #pragma unroll
  for (int off = 32; off; off >>= 1) p += __shfl_down(p, off);
  if (lane == 0) lg[c] = p + fc2_b[c];
  __syncthreads();
  if (tid == 0) {
    float m = fmaxf(lg[0], fmaxf(lg[1], lg[2]));
    float e0 = __expf(lg[0]-m), e1 = __expf(lg[1]-m), e2 = __expf(lg[2]-m);
    float s = e0 + e1 + e2;
    out[b*3 + 0] = e0/s; out[b*3 + 1] = e1/s; out[b*3 + 2] = e2/s;
  }
}

// ---------------- host ----------------
extern "C" void kernel_launch(void* const* d_in, const int* in_sizes, int n_in,
                              void* d_out, int out_size, void* d_ws, size_t ws_size,
                              hipStream_t stream)
{
  const int*   text    = (const int*)d_in[0];
  const int*   aspect  = (const int*)d_in[1];
  const int*   left    = (const int*)d_in[2];
  const float* emb     = (const float*)d_in[3];
  const float* Wih_f   = (const float*)d_in[4];
  const float* Whh_f   = (const float*)d_in[5];
  const float* bih_f   = (const float*)d_in[6];
  const float* bhh_f   = (const float*)d_in[7];
  const float* Wih_b   = (const float*)d_in[8];
  const float* Whh_b   = (const float*)d_in[9];
  const float* bih_b   = (const float*)d_in[10];
  const float* bhh_b   = (const float*)d_in[11];
  const float* w1      = (const float*)d_in[12];
  const float* w2      = (const float*)d_in[13];
  const float* fc1_w   = (const float*)d_in[14];
  const float* fc1_b   = (const float*)d_in[15];
  const float* fc2_w   = (const float*)d_in[16];
  const float* fc2_b   = (const float*)d_in[17];
  float* out = (float*)d_out;

  char* base = (char*)d_ws;
  size_t off = 0;
  auto alloc = [&](size_t bytes) -> void* {
    void* p = base + off;
    off = (off + bytes + 255) & ~(size_t)255;
    return p;
  };
  int*      lens     = (int*)     alloc(3 * NB * sizeof(int));
  float*    bias_sum = (float*)   alloc(NPAD * sizeof(float));
  _Float16* Wih16    = (_Float16*)alloc((size_t)NPAD*KP * sizeof(_Float16));     // 1.56 MB
  _Float16* Whh16    = (_Float16*)alloc((size_t)NPAD*KP * sizeof(_Float16));     // 1.56 MB
  float*    c_avg    = (float*)   alloc((size_t)NB*600 * sizeof(float));
  float*    a_avg    = (float*)   alloc((size_t)NB*600 * sizeof(float));
  float*    s1       = (float*)   alloc((size_t)NB*600 * sizeof(float));
  float*    s2       = (float*)   alloc((size_t)NB*600 * sizeof(float));
  float*    mca      = (float*)   alloc((size_t)NB*600 * sizeof(float));
  float*    mcc      = (float*)   alloc((size_t)NB*600 * sizeof(float));
  float*    mfa      = (float*)   alloc((size_t)NB*600 * sizeof(float));
  float*    mfc      = (float*)   alloc((size_t)NB*600 * sizeof(float));
  // hseqC region (39.3 MB) doubles as emb16 (20.5 MB) before the scans
  _Float16* hseqC    = (_Float16*)alloc((size_t)2*NS*NB*NH * sizeof(_Float16));
  _Float16* emb16    = hseqC;
  _Float16* hseqA    = (_Float16*)alloc((size_t)2*NA*NB*NH * sizeof(_Float16));  // 2.46 MB
  // BIG region: padded P (169 MB), overlaid later by ctx/ctxT/aspc (81 MB)
  char* bigBase = (char*)alloc((size_t)TOK_ALL * PPITCH * sizeof(_Float16));
  _Float16* P    = (_Float16*)bigBase;
  _Float16* ctx  = (_Float16*)bigBase;
  _Float16* ctxT = ctx  + (size_t)NB*NS*600;
  _Float16* aspc = ctxT + (size_t)NB*NS*600;
  if (ws_size < off) return;  // clean zero-output signal instead of OOB

  k_lengths<<<1, 256, 0, stream>>>(text, aspect, left, lens);
  k_cvt_emb<<<2048, 256, 0, stream>>>(emb, emb16);
  k_cvt_w<<<dim3(512, 3), 256, 0, stream>>>(Wih_f, Wih_b, Whh_f, Whh_b,
                                            bih_f, bhh_f, bih_b, bhh_b,
                                            Wih16, Whh16, bias_sum);
  k_inproj<<<dim3(272, 19), 256, 0, stream>>>(emb16, text, aspect, Wih16, bias_sum, P);

  k_lstm_scan<<<dim3(16, 2, 2), 1024, 0, stream>>>(P, Whh16, lens, hseqC, hseqA);

  k_combine_ctx<<<dim3(128, 16), 320, 0, stream>>>(hseqC, lens, ctx);
  k_transpose<<<dim3(256, 4, 19), 256, 0, stream>>>(ctx, ctxT);
  k_combine_asp<<<256, 320, 0, stream>>>(hseqA, lens, aspc);
  k_avg<<<256, 640, 0, stream>>>(ctx, aspc, lens, c_avg, a_avg);
  k_sw<<<dim3(32, 2), 640, 0, stream>>>(a_avg, c_avg, w1, w2, s1, s2);
  k_att_ctx<<<256, 128, 0, stream>>>(ctxT, ctx, s1, mca);
  k_att_asp<<<256, 512, 0, stream>>>(aspc, s2, mcc);
  k_u<<<256, 128, 0, stream>>>(ctxT, ctx, aspc, fc1_w, fc1_b, mfa, mfc);
  k_final<<<256, 192, 0, stream>>>(mca, mcc, mfa, mfc, fc2_w, fc2_b, out);
}